// Round 16
// baseline (167.389 us; speedup 1.0000x reference)
//
#include <hip/hip_runtime.h>
#include <stdint.h>

// PoissonNeuronTransform — bit-exact vs the harness's NUMPY reference (ref=np).
// Validated (absmax 0.0, R11-R15): threefry2x32 partitionable bits, uniform
// bit-trick, branchless fdlibm log1pf, double-reciprocal division, +0.002f,
// sequential f32 cumsum, early exit (monotone RN-fadd), ballot lane-refill.
// Round 16 (perf only): PREFETCHED work-stealing. R15's blocking
// atomic+readfirstlane (wave-wide vmcnt(0) stall per 32 elements) is split:
// the atomicAdd for the NEXT chunk is issued right after the current chunk
// installs; readfirstlane (the waitcnt point) happens ~5 iterations later
// when the pool drains -> atomic latency fully hidden by compute.

static constexpr int      kElems   = 256 * 32 * 128;   // 1048576 = 2^20
static constexpr int      kSpikes  = 100;              // NUM_SPIKES
static constexpr int      kBlocks  = 2048;             // x256 thr = 8192 waves
static constexpr uint32_t kRegions = 16;
static constexpr uint32_t kRegionSz = (uint32_t)kElems / kRegions;  // 65536
static constexpr uint32_t kChunk   = 32;

__device__ __forceinline__ uint32_t rotl32(uint32_t v, uint32_t d) {
  return (v << d) | (v >> (32u - d));
}

// threefry2x32 with key (0, 42) — matches jax.random.key(42).
__device__ __forceinline__ void threefry2x32_0_42(uint32_t x0, uint32_t x1,
                                                  uint32_t& o0, uint32_t& o1) {
  const uint32_t ks0 = 0u;
  const uint32_t ks1 = 42u;
  const uint32_t ks2 = 0x1BD11BDAu ^ 0u ^ 42u;
  uint32_t a = x0 + ks0;
  uint32_t b = x1 + ks1;
#define TF_ROUND(r) { a += b; b = rotl32(b, (r)); b ^= a; }
  TF_ROUND(13u) TF_ROUND(15u) TF_ROUND(26u) TF_ROUND(6u)
  a += ks1; b += ks2 + 1u;
  TF_ROUND(17u) TF_ROUND(29u) TF_ROUND(16u) TF_ROUND(24u)
  a += ks2; b += ks0 + 2u;
  TF_ROUND(13u) TF_ROUND(15u) TF_ROUND(26u) TF_ROUND(6u)
  a += ks0; b += ks1 + 3u;
  TF_ROUND(17u) TF_ROUND(29u) TF_ROUND(16u) TF_ROUND(24u)
  a += ks1; b += ks2 + 4u;
  TF_ROUND(13u) TF_ROUND(15u) TF_ROUND(26u) TF_ROUND(6u)
  a += ks2; b += ks0 + 5u;
#undef TF_ROUND
  o0 = a; o1 = b;
}

// Branchless fdlibm s_log1pf for x in (-1, 0] — bit-exact port (see R12).
__device__ __forceinline__ float fdlibm_log1pf_nb(float x) {
#pragma clang fp contract(off)
  const float ln2_hi = __uint_as_float(0x3f317180u);
  const float ln2_lo = __uint_as_float(0x3717f7d1u);
  const float Lp1 = __uint_as_float(0x3F2AAAABu);
  const float Lp2 = __uint_as_float(0x3ECCCCCDu);
  const float Lp3 = __uint_as_float(0x3E924925u);
  const float Lp4 = __uint_as_float(0x3E638E29u);
  const float Lp5 = __uint_as_float(0x3E3A3325u);
  const float Lp6 = __uint_as_float(0x3E1CD04Fu);
  const float Lp7 = __uint_as_float(0x3E178897u);

  uint32_t hx = __float_as_uint(x);
  uint32_t ax = hx & 0x7fffffffu;

  float u = 1.0f + x;
  uint32_t hu = __float_as_uint(u);
  int k = (int)(hu >> 23) - 127;
  float c = x - (u - 1.0f);
  c = c / u;                              // f32 IEEE div
  uint32_t m = hu & 0x007fffffu;
  bool half = (m >= 0x3504f7u);
  int k2 = half ? (k + 1) : k;
  float u2 = __uint_as_float(m | (half ? 0x3f000000u : 0x3f800000u));
  float f2 = u2 - 1.0f;

  bool cond0 = ((int32_t)hx <= (int32_t)0xbe95f61fu);
  float kf = cond0 ? 0.0f : (float)k2;
  float ff = cond0 ? x : f2;
  float cc = cond0 ? 0.0f : c;

  float hfsq = (0.5f * ff) * ff;
  float s = ff / (2.0f + ff);             // f32 IEEE div
  float z = s * s;
  float R = z * (Lp1 + z * (Lp2 + z * (Lp3 + z * (Lp4 +
            z * (Lp5 + z * (Lp6 + z * Lp7))))));
  float lowsum = s * (hfsq + R) + (kf * ln2_lo + cc);
  float res = kf * ln2_hi - ((hfsq - lowsum) - ff);

  float tiny2 = x - (x * x) * 0.5f;
  res = (ax < 0x38000000u) ? ((ax < 0x33800000u) ? x : tiny2) : res;
  return res;
}

__global__ void __launch_bounds__(256) poisson_count_kernel(
    const float* __restrict__ rates, int* __restrict__ out,
    uint32_t* __restrict__ ctrs) {
#pragma clang fp contract(off)
  int wid  = blockIdx.x * 4 + ((int)threadIdx.x >> 6);
  int lane = (int)threadIdx.x & 63;
  uint32_t region = (uint32_t)wid & (kRegions - 1u);
  uint32_t region_start = region * kRegionSz;
  uint32_t* ctr = ctrs + region * 16;      // 64 B apart
  uint64_t lmask_lt = (1ull << lane) - 1ull;

  // wave-uniform pool state
  uint32_t pool_base = 0, pool_cnt = 0;
  bool drained = false;

  // prefetched chunk grab: value lives in lane 0's VGPR until consumed
  uint32_t pending_v = 0u;
  bool have_pending = true;
  if (lane == 0) pending_v = atomicAdd(ctr, kChunk);   // initial grab (async)

  // per-lane element state
  uint32_t o = 0;
  float run = 0.0f;
  int cnt = 0, s = 0;
  double inv_d = 0.0;
  bool active = false;

  while (true) {
    uint64_t needmask = __ballot(!active);
    if (needmask != 0ull) {                       // wave-uniform
      if (pool_cnt == 0u && have_pending) {       // consume prefetched grab
        uint32_t base = __builtin_amdgcn_readfirstlane(pending_v);
        have_pending = false;
        if (base >= kRegionSz) {
          drained = true;
        } else {
          pool_base = region_start + base;
          pool_cnt = kChunk;                      // kChunk | kRegionSz
          // prefetch NEXT chunk now; waitcnt deferred to next consume
          if (lane == 0) pending_v = atomicAdd(ctr, kChunk);
          have_pending = true;
        }
      }
      if (pool_cnt != 0u) {
        if (!active) {
          uint32_t rank = (uint32_t)__popcll(needmask & lmask_lt);
          if (rank < pool_cnt) {
            o = pool_base + rank;
            float rate = rates[o];
            inv_d = 1.0 / (double)rate;           // CR f64 reciprocal
            run = 0.0f; cnt = 0; s = 0;
            active = true;
          }
        }
        uint32_t nneed = (uint32_t)__popcll(needmask);
        uint32_t handed = (nneed < pool_cnt) ? nneed : pool_cnt;
        pool_base += handed;
        pool_cnt -= handed;
      } else if (drained && needmask == ~0ull) {
        break;                                    // no work left anywhere
      }
    }

    if (active) {
      uint32_t j = ((uint32_t)s << 20) + o;       // kElems == 2^20
      uint32_t b1, b2;
      threefry2x32_0_42(0u, j, b1, b2);
      uint32_t bits = b1 ^ b2;
      float uu = __uint_as_float((bits >> 9) | 0x3f800000u) - 1.0f;  // [0, 1)
      float expo = -fdlibm_log1pf_nb(-uu);
      float q = (float)((double)expo * inv_d);    // == expo / rate (IEEE f32)
      float delta = q + 0.002f;
      run = run + delta;                          // sequential f32 cumsum
      cnt += (run < 1.0f) ? 1 : 0;
      s += 1;
      if (!(run < 1.0f) || s == kSpikes) {        // early exit (monotone) / cap
        out[o] = cnt;
        active = false;
      }
    }
  }
}

extern "C" void kernel_launch(void* const* d_in, const int* in_sizes, int n_in,
                              void* d_out, int out_size, void* d_ws, size_t ws_size,
                              hipStream_t stream) {
  const float* rates = (const float*)d_in[0];
  int* out = (int*)d_out;
  (void)in_sizes; (void)n_in; (void)out_size; (void)ws_size;
  hipMemsetAsync(d_ws, 0, kRegions * 16 * sizeof(uint32_t), stream);
  poisson_count_kernel<<<kBlocks, 256, 0, stream>>>(rates, out,
                                                    (uint32_t*)d_ws);
}

// Round 17
// 124.976 us; speedup vs baseline: 1.3394x; 1.3394x over previous
//
#include <hip/hip_runtime.h>
#include <stdint.h>

// PoissonNeuronTransform — bit-exact vs the harness's NUMPY reference (ref=np).
// Validated (absmax 0.0, R11-R16): threefry2x32 partitionable bits, uniform
// bit-trick, fdlibm log1pf port, double-reciprocal division, +0.002f,
// sequential f32 cumsum, early exit (monotone RN-fadd), wave-internal
// ballot lane-refill over a 128-element static pool (R14 structure — the
// work-stealing variants R15/R16 regressed: atomic round-trip + machinery
// cost more than the tail they recover).
// Round 17: DEAD-BRANCH ELIMINATION in fdlibm, proven on our input set:
//   uu = m*2^-23 (bit-trick) => u = 1 - uu is an exact multiple of 2^-23 in
//   [2^-23, 1] => representable => u = 1+x EXACT => c = x-(u-1) == +0 and
//   c/u == +0 for every draw. The entire c machinery (2 fsubs + one IEEE f32
//   div sequence) is removed; dropping "+cc" is bit-safe (RN: a + (+0) = a;
//   kf*ln2_lo is never -0 since kf = (float)k2, k2 <= 0).

static constexpr int      kElems  = 256 * 32 * 128;   // 1048576 = 2^20
static constexpr int      kSpikes = 100;              // NUM_SPIKES
static constexpr int      kBlocks = 2048;             // x256 thr = 8192 waves
static constexpr uint32_t kEPW    = (uint32_t)kElems / (kBlocks * 4);  // 128

__device__ __forceinline__ uint32_t rotl32(uint32_t v, uint32_t d) {
  return (v << d) | (v >> (32u - d));
}

// threefry2x32 with key (0, 42) — matches jax.random.key(42).
__device__ __forceinline__ void threefry2x32_0_42(uint32_t x0, uint32_t x1,
                                                  uint32_t& o0, uint32_t& o1) {
  const uint32_t ks0 = 0u;
  const uint32_t ks1 = 42u;
  const uint32_t ks2 = 0x1BD11BDAu ^ 0u ^ 42u;
  uint32_t a = x0 + ks0;
  uint32_t b = x1 + ks1;
#define TF_ROUND(r) { a += b; b = rotl32(b, (r)); b ^= a; }
  TF_ROUND(13u) TF_ROUND(15u) TF_ROUND(26u) TF_ROUND(6u)
  a += ks1; b += ks2 + 1u;
  TF_ROUND(17u) TF_ROUND(29u) TF_ROUND(16u) TF_ROUND(24u)
  a += ks2; b += ks0 + 2u;
  TF_ROUND(13u) TF_ROUND(15u) TF_ROUND(26u) TF_ROUND(6u)
  a += ks0; b += ks1 + 3u;
  TF_ROUND(17u) TF_ROUND(29u) TF_ROUND(16u) TF_ROUND(24u)
  a += ks1; b += ks2 + 4u;
  TF_ROUND(13u) TF_ROUND(15u) TF_ROUND(26u) TF_ROUND(6u)
  a += ks2; b += ks0 + 5u;
#undef TF_ROUND
  o0 = a; o1 = b;
}

// Branchless fdlibm s_log1pf for x = -m*2^-23, m in [0, 2^23) — bit-exact
// (R12 port, validated absmax 0) with the c-correction removed (c == +0 on
// this input set, proof in header). One IEEE f32 div remains: s = f/(2+f).
__device__ __forceinline__ float fdlibm_log1pf_nb(float x) {
#pragma clang fp contract(off)
  const float ln2_hi = __uint_as_float(0x3f317180u);
  const float ln2_lo = __uint_as_float(0x3717f7d1u);
  const float Lp1 = __uint_as_float(0x3F2AAAABu);
  const float Lp2 = __uint_as_float(0x3ECCCCCDu);
  const float Lp3 = __uint_as_float(0x3E924925u);
  const float Lp4 = __uint_as_float(0x3E638E29u);
  const float Lp5 = __uint_as_float(0x3E3A3325u);
  const float Lp6 = __uint_as_float(0x3E1CD04Fu);
  const float Lp7 = __uint_as_float(0x3E178897u);

  uint32_t hx = __float_as_uint(x);
  uint32_t ax = hx & 0x7fffffffu;

  // k != 0 machinery (u = 1+x is EXACT on our inputs => c == +0, dropped)
  float u = 1.0f + x;
  uint32_t hu = __float_as_uint(u);
  int k = (int)(hu >> 23) - 127;
  uint32_t m = hu & 0x007fffffu;
  bool half = (m >= 0x3504f7u);
  int k2 = half ? (k + 1) : k;
  float u2 = __uint_as_float(m | (half ? 0x3f000000u : 0x3f800000u));
  float f2 = u2 - 1.0f;

  // k == 0 region: x > -0.29289323 (fdlibm: (int)hx <= (int)0xbe95f61f)
  bool cond0 = ((int32_t)hx <= (int32_t)0xbe95f61fu);
  float kf = cond0 ? 0.0f : (float)k2;
  float ff = cond0 ? x : f2;

  // shared fdlibm tail (cc == +0 dropped from lowsum; bit-safe)
  float hfsq = (0.5f * ff) * ff;
  float s = ff / (2.0f + ff);             // f32 IEEE div (the only one left)
  float z = s * s;
  float R = z * (Lp1 + z * (Lp2 + z * (Lp3 + z * (Lp4 +
            z * (Lp5 + z * (Lp6 + z * Lp7))))));
  float lowsum = s * (hfsq + R) + kf * ln2_lo;
  float res = kf * ln2_hi - ((hfsq - lowsum) - ff);

  // tiny-|x| overrides (x granularity 2^-23 makes these reachable but rare)
  float tiny2 = x - (x * x) * 0.5f;
  res = (ax < 0x38000000u) ? ((ax < 0x33800000u) ? x : tiny2) : res;
  return res;
}

__global__ void __launch_bounds__(256) poisson_count_kernel(
    const float* __restrict__ rates, int* __restrict__ out) {
#pragma clang fp contract(off)
  int wid  = blockIdx.x * 4 + ((int)threadIdx.x >> 6);
  int lane = (int)threadIdx.x & 63;
  uint32_t base = (uint32_t)wid * kEPW;
  uint32_t next = 0;                       // wave-uniform: elements handed out
  uint64_t lmask_lt = (1ull << lane) - 1ull;

  // per-lane element state
  uint32_t o = 0;
  float run = 0.0f;
  int cnt = 0, s = 0;
  double inv_d = 0.0;
  bool active = false;

  while (true) {
    uint64_t needmask = __ballot(!active);
    if (needmask != 0ull) {
      uint32_t avail = kEPW - next;
      if (avail != 0u) {
        if (!active) {
          uint32_t rank = (uint32_t)__popcll(needmask & lmask_lt);
          if (rank < avail) {
            o = base + next + rank;
            float rate = rates[o];
            inv_d = 1.0 / (double)rate;    // CR f64 reciprocal (per element)
            run = 0.0f; cnt = 0; s = 0;
            active = true;
          }
        }
        uint32_t nneed = (uint32_t)__popcll(needmask);
        next += (nneed < avail) ? nneed : avail;
      } else if (needmask == ~0ull) {
        break;                             // pool empty, all lanes idle
      }
    }

    if (active) {
      uint32_t j = ((uint32_t)s << 20) + o;   // kElems == 2^20
      uint32_t b1, b2;
      threefry2x32_0_42(0u, j, b1, b2);
      uint32_t bits = b1 ^ b2;
      float uu = __uint_as_float((bits >> 9) | 0x3f800000u) - 1.0f;  // [0, 1)
      float expo = -fdlibm_log1pf_nb(-uu);
      float q = (float)((double)expo * inv_d);  // == expo / rate (IEEE f32)
      float delta = q + 0.002f;
      run = run + delta;                   // sequential f32 cumsum
      cnt += (run < 1.0f) ? 1 : 0;
      s += 1;
      if (!(run < 1.0f) || s == kSpikes) { // early exit (monotone) or cap
        out[o] = cnt;
        active = false;
      }
    }
  }
}

extern "C" void kernel_launch(void* const* d_in, const int* in_sizes, int n_in,
                              void* d_out, int out_size, void* d_ws, size_t ws_size,
                              hipStream_t stream) {
  const float* rates = (const float*)d_in[0];
  int* out = (int*)d_out;
  (void)in_sizes; (void)n_in; (void)out_size; (void)d_ws; (void)ws_size;
  poisson_count_kernel<<<kBlocks, 256, 0, stream>>>(rates, out);
}

// Round 18
// 110.999 us; speedup vs baseline: 1.5080x; 1.1259x over previous
//
#include <hip/hip_runtime.h>
#include <stdint.h>

// PoissonNeuronTransform — bit-exact vs the harness's NUMPY reference (ref=np).
// Validated (absmax 0.0, R11-R17): threefry2x32 partitionable bits, uniform
// bit-trick, fdlibm log1pf port with proven-dead c-branch removed, double-
// reciprocal division, +0.002f, sequential f32 cumsum, early exit (monotone
// RN-fadd), wave-internal ballot lane-refill over a 128-element static pool.
// Round 18 (perf only): LPT HANDOUT. Per-wave one-time bucketing of the 128
// elements into 8 descending-rate bins (ballot/popc prefix -> LDS perm+rate).
// Handing out long jobs first shrinks the end-of-pool drain tail from ~29
// rounds (random order: a rate~20 element among the last handed) to ~5
// (drain jobs all have rate < 2.5). Permutation only changes lane->element
// assignment; element math depends solely on o and rates[o] -> bit-exact.

static constexpr int      kElems  = 256 * 32 * 128;   // 1048576 = 2^20
static constexpr int      kSpikes = 100;              // NUM_SPIKES
static constexpr int      kBlocks = 2048;             // x256 thr = 8192 waves
static constexpr uint32_t kEPW    = 128;              // elements per wave

__device__ __forceinline__ uint32_t rotl32(uint32_t v, uint32_t d) {
  return (v << d) | (v >> (32u - d));
}

// threefry2x32 with key (0, 42) — matches jax.random.key(42).
__device__ __forceinline__ void threefry2x32_0_42(uint32_t x0, uint32_t x1,
                                                  uint32_t& o0, uint32_t& o1) {
  const uint32_t ks0 = 0u;
  const uint32_t ks1 = 42u;
  const uint32_t ks2 = 0x1BD11BDAu ^ 0u ^ 42u;
  uint32_t a = x0 + ks0;
  uint32_t b = x1 + ks1;
#define TF_ROUND(r) { a += b; b = rotl32(b, (r)); b ^= a; }
  TF_ROUND(13u) TF_ROUND(15u) TF_ROUND(26u) TF_ROUND(6u)
  a += ks1; b += ks2 + 1u;
  TF_ROUND(17u) TF_ROUND(29u) TF_ROUND(16u) TF_ROUND(24u)
  a += ks2; b += ks0 + 2u;
  TF_ROUND(13u) TF_ROUND(15u) TF_ROUND(26u) TF_ROUND(6u)
  a += ks0; b += ks1 + 3u;
  TF_ROUND(17u) TF_ROUND(29u) TF_ROUND(16u) TF_ROUND(24u)
  a += ks1; b += ks2 + 4u;
  TF_ROUND(13u) TF_ROUND(15u) TF_ROUND(26u) TF_ROUND(6u)
  a += ks2; b += ks0 + 5u;
#undef TF_ROUND
  o0 = a; o1 = b;
}

// Branchless fdlibm s_log1pf for x = -m*2^-23, m in [0, 2^23) — bit-exact
// (R12 port) with the c-correction removed (c == +0 on this input set: u=1+x
// is an exact multiple of 2^-23, proof in R17). One IEEE f32 div remains.
__device__ __forceinline__ float fdlibm_log1pf_nb(float x) {
#pragma clang fp contract(off)
  const float ln2_hi = __uint_as_float(0x3f317180u);
  const float ln2_lo = __uint_as_float(0x3717f7d1u);
  const float Lp1 = __uint_as_float(0x3F2AAAABu);
  const float Lp2 = __uint_as_float(0x3ECCCCCDu);
  const float Lp3 = __uint_as_float(0x3E924925u);
  const float Lp4 = __uint_as_float(0x3E638E29u);
  const float Lp5 = __uint_as_float(0x3E3A3325u);
  const float Lp6 = __uint_as_float(0x3E1CD04Fu);
  const float Lp7 = __uint_as_float(0x3E178897u);

  uint32_t hx = __float_as_uint(x);
  uint32_t ax = hx & 0x7fffffffu;

  float u = 1.0f + x;
  uint32_t hu = __float_as_uint(u);
  int k = (int)(hu >> 23) - 127;
  uint32_t m = hu & 0x007fffffu;
  bool half = (m >= 0x3504f7u);
  int k2 = half ? (k + 1) : k;
  float u2 = __uint_as_float(m | (half ? 0x3f000000u : 0x3f800000u));
  float f2 = u2 - 1.0f;

  bool cond0 = ((int32_t)hx <= (int32_t)0xbe95f61fu);
  float kf = cond0 ? 0.0f : (float)k2;
  float ff = cond0 ? x : f2;

  float hfsq = (0.5f * ff) * ff;
  float s = ff / (2.0f + ff);             // f32 IEEE div (the only one left)
  float z = s * s;
  float R = z * (Lp1 + z * (Lp2 + z * (Lp3 + z * (Lp4 +
            z * (Lp5 + z * (Lp6 + z * Lp7))))));
  float lowsum = s * (hfsq + R) + kf * ln2_lo;
  float res = kf * ln2_hi - ((hfsq - lowsum) - ff);

  float tiny2 = x - (x * x) * 0.5f;
  res = (ax < 0x38000000u) ? ((ax < 0x33800000u) ? x : tiny2) : res;
  return res;
}

__global__ void __launch_bounds__(256) poisson_count_kernel(
    const float* __restrict__ rates, int* __restrict__ out) {
#pragma clang fp contract(off)
  __shared__ uint2 pool[4][kEPW];          // {local idx, rate bits} per wave
  int wslot = (int)threadIdx.x >> 6;
  int lane  = (int)threadIdx.x & 63;
  int wid   = blockIdx.x * 4 + wslot;
  uint32_t base = (uint32_t)wid * kEPW;
  uint64_t lmask_lt = (1ull << lane) - 1ull;

  // ---- one-time LPT setup: 8 descending-rate buckets -> LDS permutation ----
  {
    float r0 = rates[base + (uint32_t)lane];
    float r1 = rates[base + 64u + (uint32_t)lane];
    // bucket 0 = highest rates ... 7 = lowest (2.5 Hz bins)
    int q0 = (int)(r0 * 0.4f); q0 = q0 > 7 ? 7 : q0;
    int q1 = (int)(r1 * 0.4f); q1 = q1 > 7 ? 7 : q1;
    int b0 = 7 - q0, b1 = 7 - q1;
    uint32_t off = 0, pos0 = 0, pos1 = 0;
#pragma unroll
    for (int b = 0; b < 8; ++b) {
      uint64_t mA = __ballot(b0 == b);
      uint64_t mB = __ballot(b1 == b);
      uint32_t cA = (uint32_t)__popcll(mA);
      if (b0 == b) pos0 = off + (uint32_t)__popcll(mA & lmask_lt);
      if (b1 == b) pos1 = off + cA + (uint32_t)__popcll(mB & lmask_lt);
      off += cA + (uint32_t)__popcll(mB);
    }
    pool[wslot][pos0] = make_uint2((uint32_t)lane, __float_as_uint(r0));
    pool[wslot][pos1] = make_uint2(64u + (uint32_t)lane, __float_as_uint(r1));
  }
  __syncthreads();

  // ---- main loop: R14/R17 structure, handout reads the LDS permutation ----
  uint32_t next = 0;                       // wave-uniform: elements handed out
  uint32_t o = 0;
  float run = 0.0f;
  int cnt = 0, s = 0;
  double inv_d = 0.0;
  bool active = false;

  while (true) {
    uint64_t needmask = __ballot(!active);
    if (needmask != 0ull) {
      uint32_t avail = kEPW - next;
      if (avail != 0u) {
        if (!active) {
          uint32_t rank = (uint32_t)__popcll(needmask & lmask_lt);
          if (rank < avail) {
            uint2 e = pool[wslot][next + rank];
            o = base + e.x;
            float rate = __uint_as_float(e.y);
            inv_d = 1.0 / (double)rate;    // CR f64 reciprocal (per element)
            run = 0.0f; cnt = 0; s = 0;
            active = true;
          }
        }
        uint32_t nneed = (uint32_t)__popcll(needmask);
        next += (nneed < avail) ? nneed : avail;
      } else if (needmask == ~0ull) {
        break;                             // pool empty, all lanes idle
      }
    }

    if (active) {
      uint32_t j = ((uint32_t)s << 20) + o;   // kElems == 2^20
      uint32_t b1, b2;
      threefry2x32_0_42(0u, j, b1, b2);
      uint32_t bits = b1 ^ b2;
      float uu = __uint_as_float((bits >> 9) | 0x3f800000u) - 1.0f;  // [0, 1)
      float expo = -fdlibm_log1pf_nb(-uu);
      float q = (float)((double)expo * inv_d);  // == expo / rate (IEEE f32)
      float delta = q + 0.002f;
      run = run + delta;                   // sequential f32 cumsum
      cnt += (run < 1.0f) ? 1 : 0;
      s += 1;
      if (!(run < 1.0f) || s == kSpikes) { // early exit (monotone) or cap
        out[o] = cnt;
        active = false;
      }
    }
  }
}

extern "C" void kernel_launch(void* const* d_in, const int* in_sizes, int n_in,
                              void* d_out, int out_size, void* d_ws, size_t ws_size,
                              hipStream_t stream) {
  const float* rates = (const float*)d_in[0];
  int* out = (int*)d_out;
  (void)in_sizes; (void)n_in; (void)out_size; (void)d_ws; (void)ws_size;
  poisson_count_kernel<<<kBlocks, 256, 0, stream>>>(rates, out);
}

// Round 19
// 107.926 us; speedup vs baseline: 1.5510x; 1.0285x over previous
//
#include <hip/hip_runtime.h>
#include <stdint.h>

// PoissonNeuronTransform — bit-exact vs the harness's NUMPY reference (ref=np).
// Validated (absmax 0.0, R11-R18): threefry2x32 partitionable bits, uniform
// bit-trick, fdlibm log1pf port (dead c-branch removed, proof R17), double-
// reciprocal division, +0.002f, sequential f32 cumsum, early exit (monotone
// RN-fadd), wave-internal ballot lane-refill, LPT (descending-rate) handout.
// Round 19 (perf only): HOIST the per-element f64 reciprocal into the
// one-time setup. Previously 1.0/(double)rate issued its ~15-20-inst f64 div
// sequence inside the refill block nearly every round (exec-masked lanes
// still cost whole-wave issue slots). Now all 128 inv_d are computed once
// (2 divs/lane, amortized over ~29 rounds) and stored in LDS beside the LPT
// permutation; refill is two LDS reads. Same computation, same value,
// hoisted -> bit-exact.

static constexpr int      kElems  = 256 * 32 * 128;   // 1048576 = 2^20
static constexpr int      kSpikes = 100;              // NUM_SPIKES
static constexpr int      kBlocks = 2048;             // x256 thr = 8192 waves
static constexpr uint32_t kEPW    = 128;              // elements per wave

__device__ __forceinline__ uint32_t rotl32(uint32_t v, uint32_t d) {
  return (v << d) | (v >> (32u - d));
}

// threefry2x32 with key (0, 42) — matches jax.random.key(42).
__device__ __forceinline__ void threefry2x32_0_42(uint32_t x0, uint32_t x1,
                                                  uint32_t& o0, uint32_t& o1) {
  const uint32_t ks0 = 0u;
  const uint32_t ks1 = 42u;
  const uint32_t ks2 = 0x1BD11BDAu ^ 0u ^ 42u;
  uint32_t a = x0 + ks0;
  uint32_t b = x1 + ks1;
#define TF_ROUND(r) { a += b; b = rotl32(b, (r)); b ^= a; }
  TF_ROUND(13u) TF_ROUND(15u) TF_ROUND(26u) TF_ROUND(6u)
  a += ks1; b += ks2 + 1u;
  TF_ROUND(17u) TF_ROUND(29u) TF_ROUND(16u) TF_ROUND(24u)
  a += ks2; b += ks0 + 2u;
  TF_ROUND(13u) TF_ROUND(15u) TF_ROUND(26u) TF_ROUND(6u)
  a += ks0; b += ks1 + 3u;
  TF_ROUND(17u) TF_ROUND(29u) TF_ROUND(16u) TF_ROUND(24u)
  a += ks1; b += ks2 + 4u;
  TF_ROUND(13u) TF_ROUND(15u) TF_ROUND(26u) TF_ROUND(6u)
  a += ks2; b += ks0 + 5u;
#undef TF_ROUND
  o0 = a; o1 = b;
}

// Branchless fdlibm s_log1pf for x = -m*2^-23, m in [0, 2^23) — bit-exact
// (R12 port) with the c-correction removed (c == +0 on this input set,
// proof R17). One IEEE f32 div remains: s = f/(2+f).
__device__ __forceinline__ float fdlibm_log1pf_nb(float x) {
#pragma clang fp contract(off)
  const float ln2_hi = __uint_as_float(0x3f317180u);
  const float ln2_lo = __uint_as_float(0x3717f7d1u);
  const float Lp1 = __uint_as_float(0x3F2AAAABu);
  const float Lp2 = __uint_as_float(0x3ECCCCCDu);
  const float Lp3 = __uint_as_float(0x3E924925u);
  const float Lp4 = __uint_as_float(0x3E638E29u);
  const float Lp5 = __uint_as_float(0x3E3A3325u);
  const float Lp6 = __uint_as_float(0x3E1CD04Fu);
  const float Lp7 = __uint_as_float(0x3E178897u);

  uint32_t hx = __float_as_uint(x);
  uint32_t ax = hx & 0x7fffffffu;

  float u = 1.0f + x;
  uint32_t hu = __float_as_uint(u);
  int k = (int)(hu >> 23) - 127;
  uint32_t m = hu & 0x007fffffu;
  bool half = (m >= 0x3504f7u);
  int k2 = half ? (k + 1) : k;
  float u2 = __uint_as_float(m | (half ? 0x3f000000u : 0x3f800000u));
  float f2 = u2 - 1.0f;

  bool cond0 = ((int32_t)hx <= (int32_t)0xbe95f61fu);
  float kf = cond0 ? 0.0f : (float)k2;
  float ff = cond0 ? x : f2;

  float hfsq = (0.5f * ff) * ff;
  float s = ff / (2.0f + ff);             // f32 IEEE div (the only one left)
  float z = s * s;
  float R = z * (Lp1 + z * (Lp2 + z * (Lp3 + z * (Lp4 +
            z * (Lp5 + z * (Lp6 + z * Lp7))))));
  float lowsum = s * (hfsq + R) + kf * ln2_lo;
  float res = kf * ln2_hi - ((hfsq - lowsum) - ff);

  float tiny2 = x - (x * x) * 0.5f;
  res = (ax < 0x38000000u) ? ((ax < 0x33800000u) ? x : tiny2) : res;
  return res;
}

__global__ void __launch_bounds__(256) poisson_count_kernel(
    const float* __restrict__ rates, int* __restrict__ out) {
#pragma clang fp contract(off)
  __shared__ uint32_t pool_idx[4][kEPW];   // local element index (LPT order)
  __shared__ double   pool_inv[4][kEPW];   // hoisted 1.0/(double)rate
  int wslot = (int)threadIdx.x >> 6;
  int lane  = (int)threadIdx.x & 63;
  int wid   = blockIdx.x * 4 + wslot;
  uint32_t base = (uint32_t)wid * kEPW;
  uint64_t lmask_lt = (1ull << lane) - 1ull;

  // ---- one-time setup: LPT buckets + hoisted f64 reciprocals ----
  {
    float r0 = rates[base + (uint32_t)lane];
    float r1 = rates[base + 64u + (uint32_t)lane];
    int q0 = (int)(r0 * 0.4f); q0 = q0 > 7 ? 7 : q0;
    int q1 = (int)(r1 * 0.4f); q1 = q1 > 7 ? 7 : q1;
    int b0 = 7 - q0, b1 = 7 - q1;          // bucket 0 = highest rates
    uint32_t off = 0, pos0 = 0, pos1 = 0;
#pragma unroll
    for (int b = 0; b < 8; ++b) {
      uint64_t mA = __ballot(b0 == b);
      uint64_t mB = __ballot(b1 == b);
      uint32_t cA = (uint32_t)__popcll(mA);
      if (b0 == b) pos0 = off + (uint32_t)__popcll(mA & lmask_lt);
      if (b1 == b) pos1 = off + cA + (uint32_t)__popcll(mB & lmask_lt);
      off += cA + (uint32_t)__popcll(mB);
    }
    pool_idx[wslot][pos0] = (uint32_t)lane;
    pool_inv[wslot][pos0] = 1.0 / (double)r0;   // CR f64 reciprocal, hoisted
    pool_idx[wslot][pos1] = 64u + (uint32_t)lane;
    pool_inv[wslot][pos1] = 1.0 / (double)r1;
  }
  __syncthreads();

  // ---- main loop: R14/R17/R18 structure; refill = two LDS reads ----
  uint32_t next = 0;                       // wave-uniform: elements handed out
  uint32_t o = 0;
  float run = 0.0f;
  int cnt = 0, s = 0;
  double inv_d = 0.0;
  bool active = false;

  while (true) {
    uint64_t needmask = __ballot(!active);
    if (needmask != 0ull) {
      uint32_t avail = kEPW - next;
      if (avail != 0u) {
        if (!active) {
          uint32_t rank = (uint32_t)__popcll(needmask & lmask_lt);
          if (rank < avail) {
            uint32_t slot = next + rank;
            o = base + pool_idx[wslot][slot];
            inv_d = pool_inv[wslot][slot];
            run = 0.0f; cnt = 0; s = 0;
            active = true;
          }
        }
        uint32_t nneed = (uint32_t)__popcll(needmask);
        next += (nneed < avail) ? nneed : avail;
      } else if (needmask == ~0ull) {
        break;                             // pool empty, all lanes idle
      }
    }

    if (active) {
      uint32_t j = ((uint32_t)s << 20) + o;   // kElems == 2^20
      uint32_t b1, b2;
      threefry2x32_0_42(0u, j, b1, b2);
      uint32_t bits = b1 ^ b2;
      float uu = __uint_as_float((bits >> 9) | 0x3f800000u) - 1.0f;  // [0, 1)
      float expo = -fdlibm_log1pf_nb(-uu);
      float q = (float)((double)expo * inv_d);  // == expo / rate (IEEE f32)
      float delta = q + 0.002f;
      run = run + delta;                   // sequential f32 cumsum
      cnt += (run < 1.0f) ? 1 : 0;
      s += 1;
      if (!(run < 1.0f) || s == kSpikes) { // early exit (monotone) or cap
        out[o] = cnt;
        active = false;
      }
    }
  }
}

extern "C" void kernel_launch(void* const* d_in, const int* in_sizes, int n_in,
                              void* d_out, int out_size, void* d_ws, size_t ws_size,
                              hipStream_t stream) {
  const float* rates = (const float*)d_in[0];
  int* out = (int*)d_out;
  (void)in_sizes; (void)n_in; (void)out_size; (void)d_ws; (void)ws_size;
  poisson_count_kernel<<<kBlocks, 256, 0, stream>>>(rates, out);
}